// Round 5
// baseline (206.374 us; speedup 1.0000x reference)
//
#include <hip/hip_runtime.h>
#include <math.h>

// SigmaMoE bf16-MFMA version, round 5.
// Pipeline (NO global atomics):
//  route_conv: fused x->bf16 convert + fp32 routing + exact top-4
//  compact:    per-expert lists via ballot-scan (deterministic)
//  trans:      keys -> ktb bf16 [16][256][1024]; values -> vtb bf16 [16][1024][256]
//  ffn<1>:     per-expert 64-token tiles; MFMA 16x16x32 bf16.
//              A-operands (X tile, S tile) via swizzled LDS; B-operands
//              (ktb/vtb rows) read DIRECTLY from global (L2-resident).
//              XCD-swizzled block mapping: 2 experts per XCD.
//  combine:    out[t] = sum_k wtk[t*4+k] * scratch[t*4+k]

constexpr int NTOK = 8192;
constexpr int DM   = 1024;
constexpr int NE   = 16;
constexpr int EH   = 256;
constexpr int TK   = 4;
constexpr int CAP  = 8192;
constexpr int TM   = 64;

typedef __attribute__((ext_vector_type(8))) short short8;
typedef __attribute__((ext_vector_type(4))) float f32x4;

#define MFMA16(a, b, c) __builtin_amdgcn_mfma_f32_16x16x32_bf16(a, b, c, 0, 0, 0)

__device__ __forceinline__ void gload_lds16(const void* g, void* l) {
    __builtin_amdgcn_global_load_lds(
        (const __attribute__((address_space(1))) void*)g,
        (__attribute__((address_space(3))) void*)l, 16, 0, 0);
}

__device__ __forceinline__ unsigned short f2bf(float f) {
    union { float f; unsigned int u; } x; x.f = f;
    unsigned int r = x.u + 0x7fffu + ((x.u >> 16) & 1u);  // RNE
    return (unsigned short)(r >> 16);
}
__device__ __forceinline__ float bf2f(unsigned short b) {
    union { unsigned int u; float f; } x; x.u = ((unsigned int)b) << 16;
    return x.f;
}

// ---------------- fused convert + routing (atomic-free) ----------------
__global__ __launch_bounds__(256) void route_conv_kernel(
    const float* __restrict__ x, const float* __restrict__ esel,
    const float* __restrict__ rscale,
    unsigned short* __restrict__ xb,
    int4* __restrict__ sel4, float* __restrict__ wtk)
{
    __shared__ float Es[NE * DM];   // 64KB
    int tid = threadIdx.x;

    {   // stage esel: 4096 float4s
        const float4* src = (const float4*)esel;
        float4* dst = (float4*)Es;
        #pragma unroll
        for (int j = 0; j < 16; ++j) dst[tid + j * 256] = src[tid + j * 256];
    }
    __syncthreads();

    int t    = blockIdx.x * 8 + (tid >> 5);
    int l32  = tid & 31;

    float acc[NE];
    #pragma unroll
    for (int e = 0; e < NE; ++e) acc[e] = 0.f;

    const float4* x4 = (const float4*)(x + (size_t)t * DM);
    const float4* E4 = (const float4*)Es;
    #pragma unroll
    for (int i4 = 0; i4 < 8; ++i4) {
        int d4 = i4 * 32 + l32;
        float4 xv = x4[d4];
        ushort4 cb = { f2bf(xv.x), f2bf(xv.y), f2bf(xv.z), f2bf(xv.w) };
        *(ushort4*)(xb + (size_t)t * DM + d4 * 4) = cb;
        #pragma unroll
        for (int e = 0; e < NE; ++e) {
            float4 wv = E4[e * 256 + d4];
            acc[e] = fmaf(xv.x, wv.x, acc[e]);
            acc[e] = fmaf(xv.y, wv.y, acc[e]);
            acc[e] = fmaf(xv.z, wv.z, acc[e]);
            acc[e] = fmaf(xv.w, wv.w, acc[e]);
        }
    }

    #pragma unroll
    for (int off = 16; off; off >>= 1)
        #pragma unroll
        for (int e = 0; e < NE; ++e)
            acc[e] += __shfl_xor(acc[e], off, 32);

    if (l32 == 0) {
        float p[NE];
        #pragma unroll
        for (int e = 0; e < NE; ++e) p[e] = 1.0f / (1.0f + expf(-acc[e]));

        int   sel_e[TK];
        float sel_p[TK];
        float sum = 0.f;
        #pragma unroll
        for (int k = 0; k < TK; ++k) {
            float best = -INFINITY; int be = NE;
            #pragma unroll
            for (int e = 0; e < NE; ++e) {
                bool take = p[e] > best;
                best = take ? p[e] : best;
                be   = take ? e    : be;
            }
            sel_e[k] = be; sel_p[k] = best; sum += best;
            #pragma unroll
            for (int e = 0; e < NE; ++e) p[e] = (e == be) ? -INFINITY : p[e];
        }

        float wsc = rscale[0] / fmaxf(sum, 1e-9f);
        int4 s = { sel_e[0], sel_e[1], sel_e[2], sel_e[3] };
        sel4[t] = s;
        float4 wv = { sel_p[0] * wsc, sel_p[1] * wsc,
                      sel_p[2] * wsc, sel_p[3] * wsc };
        *(float4*)(wtk + t * TK) = wv;
    }
}

// ---------------- compact: per-expert lists, atomic-free ----------------
__global__ __launch_bounds__(1024) void compact_kernel(
    const int4* __restrict__ sel4, int* __restrict__ counts,
    int* __restrict__ lpk)
{
    __shared__ int wsum[16];
    int e    = blockIdx.x;
    int tid  = threadIdx.x;
    int w    = tid >> 6;
    int lane = tid & 63;

    int base = 0;
    for (int c = 0; c < NTOK; c += 1024) {
        int t = c + tid;
        int4 s = sel4[t];
        int k = -1;
        if      (s.x == e) k = 0;
        else if (s.y == e) k = 1;
        else if (s.z == e) k = 2;
        else if (s.w == e) k = 3;
        unsigned long long m = __ballot(k >= 0);
        int rank = __popcll(m & ((1ull << lane) - 1ull));
        if (lane == 63) wsum[w] = __popcll(m);
        __syncthreads();
        int prefix = 0, total = 0;
        #pragma unroll
        for (int i = 0; i < 16; ++i) {
            int v = wsum[i];
            prefix += (i < w) ? v : 0;
            total  += v;
        }
        if (k >= 0) lpk[e * CAP + base + prefix + rank] = t * TK + k;
        base += total;
        __syncthreads();
    }
    if (tid == 0) counts[e] = base;
}

// in [E][R][C] f32 -> out [E][C][R] bf16
__global__ __launch_bounds__(256) void trans_kernel(
    const float* __restrict__ in, unsigned short* __restrict__ outp, int R, int C)
{
    __shared__ float T[32][33];
    int e = blockIdx.z;
    int r0 = blockIdx.y * 32, c0 = blockIdx.x * 32;
    int ri = threadIdx.x >> 3, cq = threadIdx.x & 7;
    float4 v = *(const float4*)(in + ((size_t)e * R + r0 + ri) * C + c0 + cq * 4);
    T[ri][cq * 4 + 0] = v.x; T[ri][cq * 4 + 1] = v.y;
    T[ri][cq * 4 + 2] = v.z; T[ri][cq * 4 + 3] = v.w;
    __syncthreads();
    int ci = threadIdx.x >> 3, rq = threadIdx.x & 7;
    ushort4 o = { f2bf(T[rq * 4 + 0][ci]), f2bf(T[rq * 4 + 1][ci]),
                  f2bf(T[rq * 4 + 2][ci]), f2bf(T[rq * 4 + 3][ci]) };
    *(ushort4*)(outp + ((size_t)e * C + c0 + ci) * R + r0 + rq * 4) = o;
}

// ---------------- FFN (MFMA, global-B) ----------------
// 256 threads (4 waves); per block: expert e, 64 tokens.
// LDS: Xs[64][64] bf16 swizzled (8KB) + Ss[64][256] bf16 swizzled (32KB) + meta.
// B fragments read directly from ktb/vtb (L2). XCD-swizzle: 2 experts/XCD.
template<int USE_SCRATCH>
__global__ __launch_bounds__(256, 3) void ffn_kernel(
    const unsigned short* __restrict__ xb,
    const unsigned short* __restrict__ ktb,   // [16][256][1024]
    const unsigned short* __restrict__ vtb,   // [16][1024][256]
    const int* __restrict__ counts, const int* __restrict__ lpk,
    const float* __restrict__ wtk,
    unsigned short* __restrict__ scratch,     // [32769][1024] bf16
    float* __restrict__ out)
{
    // grid is (128, 16); remap so each XCD (dispatch id % 8) owns 2 experts
    int flat = blockIdx.y * gridDim.x + blockIdx.x;   // 0..2047
    int xcd  = flat & 7;
    int ixc  = flat >> 3;                             // 0..255
    int e    = xcd * 2 + (ixc >> 7);
    int t0   = (ixc & 127) * TM;

    int cnt = counts[e];
    if (t0 >= cnt) return;

    __shared__ __align__(16) char L[41728];
    char* Xs = L;                 // 8KB  [64][64] bf16 swizzled
    char* Ss = L + 8192;          // 32KB [64][256] bf16 swizzled
    int*   stok = (int*)(L + 40960);
    int*   spk  = (int*)(L + 41216);
    float* sw   = (float*)(L + 41472);

    int tid  = threadIdx.x;
    int lane = tid & 63;
    int w    = tid >> 6;

    if (tid < TM) {
        int s = t0 + tid;
        if (s < cnt) {
            int pk = lpk[e * CAP + s];
            stok[tid] = pk >> 2; spk[tid] = pk; sw[tid] = wtk[pk];
        } else {
            stok[tid] = 0; spk[tid] = USE_SCRATCH ? (NTOK * TK) : 0; sw[tid] = 0.f;
        }
    }
    __syncthreads();

    f32x4 zero = {0.f, 0.f, 0.f, 0.f};
    f32x4 acc[4][4];
    #pragma unroll
    for (int mi = 0; mi < 4; ++mi)
        #pragma unroll
        for (int ni = 0; ni < 4; ++ni) acc[mi][ni] = zero;

    // ---- phase 1: S = relu(X @ K_e); B from global ktb ----
    const unsigned short* kbase = ktb + (size_t)e * EH * DM;
    for (int kc = 0; kc < DM; kc += 64) {
        #pragma unroll
        for (int c = 0; c < 2; ++c) {          // stage Xs rows [w*16, +16)
            int base = (w * 16 + c * 8) * 128;
            int P = base + lane * 16;
            int row = P >> 7;
            int A = P ^ ((row & 7) << 4);
            const unsigned short* src =
                xb + (size_t)stok[A >> 7] * DM + kc + ((A & 127) >> 1);
            gload_lds16(src, Xs + base);
        }
        __syncthreads();
        #pragma unroll
        for (int kk = 0; kk < 2; ++kk) {
            short8 a[4], b[4];
            #pragma unroll
            for (int mi = 0; mi < 4; ++mi) {
                int row = mi * 16 + (lane & 15);
                int A = row * 128 + (kk * 32 + (lane >> 4) * 8) * 2;
                a[mi] = *(const short8*)(Xs + (A ^ ((row & 7) << 4)));
            }
            #pragma unroll
            for (int ni = 0; ni < 4; ++ni) {
                int h = w * 64 + ni * 16 + (lane & 15);
                b[ni] = *(const short8*)(kbase + (size_t)h * DM + kc +
                                         kk * 32 + (lane >> 4) * 8);
            }
            #pragma unroll
            for (int mi = 0; mi < 4; ++mi)
                #pragma unroll
                for (int ni = 0; ni < 4; ++ni)
                    acc[mi][ni] = MFMA16(a[mi], b[ni], acc[mi][ni]);
        }
        __syncthreads();
    }

    // relu -> Ss (bf16, swizzled); D layout: col=lane&15, row=(lane>>4)*4+r
    #pragma unroll
    for (int mi = 0; mi < 4; ++mi)
        #pragma unroll
        for (int ni = 0; ni < 4; ++ni) {
            f32x4 v = acc[mi][ni];
            #pragma unroll
            for (int r = 0; r < 4; ++r) {
                int row = mi * 16 + (lane >> 4) * 4 + r;
                int col = w * 64 + ni * 16 + (lane & 15);
                int A = row * 512 + col * 2;
                *(unsigned short*)(Ss + (A ^ ((row & 7) << 4))) =
                    f2bf(fmaxf(v[r], 0.f));
            }
        }
    __syncthreads();

    // ---- phase 2: O = S @ V_e; barrier-free; wave w owns d in [w*256,+256) ----
    const unsigned short* vbase = vtb + (size_t)e * DM * EH;
    for (int nc = 0; nc < 4; ++nc) {
        f32x4 acc2[4][4];
        #pragma unroll
        for (int mi = 0; mi < 4; ++mi)
            #pragma unroll
            for (int ni = 0; ni < 4; ++ni) acc2[mi][ni] = zero;

        #pragma unroll
        for (int kk = 0; kk < 8; ++kk) {
            short8 a[4], b[4];
            #pragma unroll
            for (int mi = 0; mi < 4; ++mi) {
                int row = mi * 16 + (lane & 15);
                int A = row * 512 + (kk * 32 + (lane >> 4) * 8) * 2;
                a[mi] = *(const short8*)(Ss + (A ^ ((row & 7) << 4)));
            }
            #pragma unroll
            for (int ni = 0; ni < 4; ++ni) {
                int d = w * 256 + nc * 64 + ni * 16 + (lane & 15);
                b[ni] = *(const short8*)(vbase + (size_t)d * EH +
                                         kk * 32 + (lane >> 4) * 8);
            }
            #pragma unroll
            for (int mi = 0; mi < 4; ++mi)
                #pragma unroll
                for (int ni = 0; ni < 4; ++ni)
                    acc2[mi][ni] = MFMA16(a[mi], b[ni], acc2[mi][ni]);
        }

        #pragma unroll
        for (int mi = 0; mi < 4; ++mi)
            #pragma unroll
            for (int ni = 0; ni < 4; ++ni) {
                f32x4 v = acc2[mi][ni];
                #pragma unroll
                for (int r = 0; r < 4; ++r) {
                    int slot = mi * 16 + (lane >> 4) * 4 + r;
                    int d = w * 256 + nc * 64 + ni * 16 + (lane & 15);
                    if (USE_SCRATCH) {
                        scratch[(size_t)spk[slot] * DM + d] = f2bf(v[r]);
                    } else {
                        atomicAdd(out + (size_t)stok[slot] * DM + d, sw[slot] * v[r]);
                    }
                }
            }
    }
}

// ---------------- combine ----------------
__global__ __launch_bounds__(256) void combine_kernel(
    const unsigned short* __restrict__ scratch, const float* __restrict__ wtk,
    float* __restrict__ out)
{
    int t  = blockIdx.x * 2 + (threadIdx.x >> 7);
    int d0 = (threadIdx.x & 127) * 8;
    float o[8] = {0.f, 0.f, 0.f, 0.f, 0.f, 0.f, 0.f, 0.f};
    #pragma unroll
    for (int k = 0; k < TK; ++k) {
        float wv = wtk[t * TK + k];
        uint4 q = *(const uint4*)(scratch + (size_t)(t * TK + k) * DM + d0);
        unsigned int us[4] = {q.x, q.y, q.z, q.w};
        #pragma unroll
        for (int j = 0; j < 4; ++j) {
            o[j * 2 + 0] = fmaf(wv, bf2f((unsigned short)(us[j] & 0xffff)), o[j * 2 + 0]);
            o[j * 2 + 1] = fmaf(wv, bf2f((unsigned short)(us[j] >> 16)),    o[j * 2 + 1]);
        }
    }
    float4 w0 = {o[0], o[1], o[2], o[3]}, w1 = {o[4], o[5], o[6], o[7]};
    *(float4*)(out + (size_t)t * DM + d0)     = w0;
    *(float4*)(out + (size_t)t * DM + d0 + 4) = w1;
}

extern "C" void kernel_launch(void* const* d_in, const int* in_sizes, int n_in,
                              void* d_out, int out_size, void* d_ws, size_t ws_size,
                              hipStream_t stream) {
    const float* x      = (const float*)d_in[0];
    const float* esel   = (const float*)d_in[1];
    const float* keys   = (const float*)d_in[2];
    const float* values = (const float*)d_in[3];
    const float* rscale = (const float*)d_in[4];
    float* out = (float*)d_out;

    char* ws = (char*)d_ws;
    size_t o = 0;
    auto alloc = [&](size_t sz) { size_t r = o; o = (o + sz + 255) & ~(size_t)255; return r; };
    size_t o_counts = alloc(NE * 4);
    size_t o_lpk    = alloc((size_t)NE * CAP * 4);
    size_t o_sel4   = alloc((size_t)NTOK * 16);
    size_t o_wtk    = alloc((size_t)NTOK * TK * 4);
    size_t o_xb     = alloc((size_t)NTOK * DM * 2);
    size_t o_ktb    = alloc((size_t)NE * EH * DM * 2);
    size_t o_vtb    = alloc((size_t)NE * DM * EH * 2);
    size_t o_scr    = alloc(((size_t)NTOK * TK + TM) * DM * 2);
    size_t need_full = o;

    int*            counts  = (int*)(ws + o_counts);
    int*            lpk     = (int*)(ws + o_lpk);
    int4*           sel4    = (int4*)(ws + o_sel4);
    float*          wtk     = (float*)(ws + o_wtk);
    unsigned short* xb      = (unsigned short*)(ws + o_xb);
    unsigned short* ktb     = (unsigned short*)(ws + o_ktb);
    unsigned short* vtb     = (unsigned short*)(ws + o_vtb);
    unsigned short* scratch = (unsigned short*)(ws + o_scr);

    bool use_scratch = ws_size >= need_full;

    if (!use_scratch)
        hipMemsetAsync(d_out, 0, (size_t)out_size * sizeof(float), stream);

    route_conv_kernel<<<NTOK / 8, 256, 0, stream>>>(x, esel, rscale, xb,
                                                    sel4, wtk);
    compact_kernel<<<NE, 1024, 0, stream>>>(sel4, counts, lpk);
    trans_kernel<<<dim3(EH / 32, DM / 32, NE), 256, 0, stream>>>(keys, ktb, DM, EH);
    trans_kernel<<<dim3(DM / 32, EH / 32, NE), 256, 0, stream>>>(values, vtb, EH, DM);

    if (use_scratch) {
        ffn_kernel<1><<<dim3(CAP / TM, NE), 256, 0, stream>>>(
            xb, ktb, vtb, counts, lpk, wtk, scratch, out);
        combine_kernel<<<NTOK / 2, 256, 0, stream>>>(scratch, wtk, out);
    } else {
        ffn_kernel<0><<<dim3(CAP / TM, NE), 256, 0, stream>>>(
            xb, ktb, vtb, counts, lpk, wtk, scratch, out);
    }
}

// Round 6
// 144.015 us; speedup vs baseline: 1.4330x; 1.4330x over previous
//
#include <hip/hip_runtime.h>
#include <math.h>

// SigmaMoE bf16-MFMA version, round 6.
// Pipeline (NO global atomics):
//  route_conv: fused x->bf16 convert + fp32 routing + exact top-4
//  compact:    per-expert lists via ballot-scan (deterministic)
//  trans:      keys -> ktb bf16 [16][256][1024]; values -> vtb bf16 [16][1024][256]
//  ffn<1>:     per-expert 128-token tiles; MFMA 16x16x32 bf16; double-buffered
//              LDS staging (T3 minimum 2-phase: stage-next before compute-cur,
//              one barrier per step); XCD-bijective block map (2 experts/XCD).
//  combine:    out[t] = sum_k wtk[t*4+k] * scratch[t*4+k]

constexpr int NTOK = 8192;
constexpr int DM   = 1024;
constexpr int NE   = 16;
constexpr int EH   = 256;
constexpr int TK   = 4;
constexpr int CAP  = 8192;
constexpr int BM   = 128;

typedef __attribute__((ext_vector_type(8))) short short8;
typedef __attribute__((ext_vector_type(4))) float f32x4;

#define MFMA16(a, b, c) __builtin_amdgcn_mfma_f32_16x16x32_bf16(a, b, c, 0, 0, 0)

__device__ __forceinline__ void gload_lds16(const void* g, void* l) {
    __builtin_amdgcn_global_load_lds(
        (const __attribute__((address_space(1))) void*)g,
        (__attribute__((address_space(3))) void*)l, 16, 0, 0);
}

__device__ __forceinline__ unsigned short f2bf(float f) {
    union { float f; unsigned int u; } x; x.f = f;
    unsigned int r = x.u + 0x7fffu + ((x.u >> 16) & 1u);  // RNE
    return (unsigned short)(r >> 16);
}
__device__ __forceinline__ float bf2f(unsigned short b) {
    union { unsigned int u; float f; } x; x.u = ((unsigned int)b) << 16;
    return x.f;
}

// ---------------- fused convert + routing (atomic-free) ----------------
__global__ __launch_bounds__(256) void route_conv_kernel(
    const float* __restrict__ x, const float* __restrict__ esel,
    const float* __restrict__ rscale,
    unsigned short* __restrict__ xb,
    int4* __restrict__ sel4, float* __restrict__ wtk)
{
    __shared__ float Es[NE * DM];   // 64KB
    int tid = threadIdx.x;

    {   // stage esel: 4096 float4s
        const float4* src = (const float4*)esel;
        float4* dst = (float4*)Es;
        #pragma unroll
        for (int j = 0; j < 16; ++j) dst[tid + j * 256] = src[tid + j * 256];
    }
    __syncthreads();

    int t    = blockIdx.x * 8 + (tid >> 5);
    int l32  = tid & 31;

    float acc[NE];
    #pragma unroll
    for (int e = 0; e < NE; ++e) acc[e] = 0.f;

    const float4* x4 = (const float4*)(x + (size_t)t * DM);
    const float4* E4 = (const float4*)Es;
    #pragma unroll
    for (int i4 = 0; i4 < 8; ++i4) {
        int d4 = i4 * 32 + l32;
        float4 xv = x4[d4];
        ushort4 cb = { f2bf(xv.x), f2bf(xv.y), f2bf(xv.z), f2bf(xv.w) };
        *(ushort4*)(xb + (size_t)t * DM + d4 * 4) = cb;
        #pragma unroll
        for (int e = 0; e < NE; ++e) {
            float4 wv = E4[e * 256 + d4];
            acc[e] = fmaf(xv.x, wv.x, acc[e]);
            acc[e] = fmaf(xv.y, wv.y, acc[e]);
            acc[e] = fmaf(xv.z, wv.z, acc[e]);
            acc[e] = fmaf(xv.w, wv.w, acc[e]);
        }
    }

    #pragma unroll
    for (int off = 16; off; off >>= 1)
        #pragma unroll
        for (int e = 0; e < NE; ++e)
            acc[e] += __shfl_xor(acc[e], off, 32);

    if (l32 == 0) {
        float p[NE];
        #pragma unroll
        for (int e = 0; e < NE; ++e) p[e] = 1.0f / (1.0f + expf(-acc[e]));

        int   sel_e[TK];
        float sel_p[TK];
        float sum = 0.f;
        #pragma unroll
        for (int k = 0; k < TK; ++k) {
            float best = -INFINITY; int be = NE;
            #pragma unroll
            for (int e = 0; e < NE; ++e) {
                bool take = p[e] > best;
                best = take ? p[e] : best;
                be   = take ? e    : be;
            }
            sel_e[k] = be; sel_p[k] = best; sum += best;
            #pragma unroll
            for (int e = 0; e < NE; ++e) p[e] = (e == be) ? -INFINITY : p[e];
        }

        float wsc = rscale[0] / fmaxf(sum, 1e-9f);
        int4 s = { sel_e[0], sel_e[1], sel_e[2], sel_e[3] };
        sel4[t] = s;
        float4 wv = { sel_p[0] * wsc, sel_p[1] * wsc,
                      sel_p[2] * wsc, sel_p[3] * wsc };
        *(float4*)(wtk + t * TK) = wv;
    }
}

// ---------------- compact: per-expert lists, atomic-free ----------------
__global__ __launch_bounds__(1024) void compact_kernel(
    const int4* __restrict__ sel4, int* __restrict__ counts,
    int* __restrict__ lpk)
{
    __shared__ int wsum[16];
    int e    = blockIdx.x;
    int tid  = threadIdx.x;
    int w    = tid >> 6;
    int lane = tid & 63;

    int base = 0;
    for (int c = 0; c < NTOK; c += 1024) {
        int t = c + tid;
        int4 s = sel4[t];
        int k = -1;
        if      (s.x == e) k = 0;
        else if (s.y == e) k = 1;
        else if (s.z == e) k = 2;
        else if (s.w == e) k = 3;
        unsigned long long m = __ballot(k >= 0);
        int rank = __popcll(m & ((1ull << lane) - 1ull));
        if (lane == 63) wsum[w] = __popcll(m);
        __syncthreads();
        int prefix = 0, total = 0;
        #pragma unroll
        for (int i = 0; i < 16; ++i) {
            int v = wsum[i];
            prefix += (i < w) ? v : 0;
            total  += v;
        }
        if (k >= 0) lpk[e * CAP + base + prefix + rank] = t * TK + k;
        base += total;
        __syncthreads();
    }
    if (tid == 0) counts[e] = base;
}

// in [E][R][C] f32 -> out [E][C][R] bf16
__global__ __launch_bounds__(256) void trans_kernel(
    const float* __restrict__ in, unsigned short* __restrict__ outp, int R, int C)
{
    __shared__ float T[32][33];
    int e = blockIdx.z;
    int r0 = blockIdx.y * 32, c0 = blockIdx.x * 32;
    int ri = threadIdx.x >> 3, cq = threadIdx.x & 7;
    float4 v = *(const float4*)(in + ((size_t)e * R + r0 + ri) * C + c0 + cq * 4);
    T[ri][cq * 4 + 0] = v.x; T[ri][cq * 4 + 1] = v.y;
    T[ri][cq * 4 + 2] = v.z; T[ri][cq * 4 + 3] = v.w;
    __syncthreads();
    int ci = threadIdx.x >> 3, rq = threadIdx.x & 7;
    ushort4 o = { f2bf(T[rq * 4 + 0][ci]), f2bf(T[rq * 4 + 1][ci]),
                  f2bf(T[rq * 4 + 2][ci]), f2bf(T[rq * 4 + 3][ci]) };
    *(ushort4*)(outp + ((size_t)e * C + c0 + ci) * R + r0 + rq * 4) = o;
}

// ---------------- FFN (MFMA, double-buffered pipeline) ----------------
// 512 threads (8 waves); per block: expert e, 128 tokens.
// LDS: Xs dbuf 2x8KB [128][32]bf16 (64B rows, swz ((row>>1)&3)<<4)
//      Ks/Vs dbuf 2x16KB [256][32]bf16 (same swz)
//      Ss 64KB [128][256]bf16 (512B rows, swz (row&7)<<4)
// Step: issue stage(next) -> compute(cur) -> __syncthreads (drain).
template<int USE_SCRATCH>
__global__ __launch_bounds__(512, 2) void ffn_kernel(
    const unsigned short* __restrict__ xb,
    const unsigned short* __restrict__ ktb,   // [16][256][1024]
    const unsigned short* __restrict__ vtb,   // [16][1024][256]
    const int* __restrict__ counts, const int* __restrict__ lpk,
    const float* __restrict__ wtk,
    unsigned short* __restrict__ scratch,     // [NTOK*TK+BM][1024] bf16
    float* __restrict__ out)
{
    // XCD-bijective map: grid 1024 = 8 xcd * 2 experts * 64 tiles
    int bid = blockIdx.x;
    int xcd = bid & 7, idx = bid >> 3;
    int e   = xcd * 2 + (idx >> 6);
    int t0  = (idx & 63) * BM;
    int cnt = counts[e];
    if (t0 >= cnt) return;

    __shared__ __align__(16) char L[116224];
    char* const Xs0 = L;
    char* const Xs1 = L + 8192;
    char* const Ks0 = L + 16384;
    char* const Ks1 = L + 32768;
    char* const Ss  = L + 49152;          // 64KB
    int*   stok = (int*)(L + 114688);
    int*   spk  = (int*)(L + 115200);
    float* sw   = (float*)(L + 115712);

    int tid  = threadIdx.x;
    int lane = tid & 63;
    int w    = tid >> 6;
    int lm   = lane & 15;
    int q    = lane >> 4;
    int th   = w >> 2;      // token half (0,1)
    int hq   = w & 3;       // h/d quarter (0..3)

    if (tid < BM) {
        int s = t0 + tid;
        if (s < cnt) {
            int pk = lpk[e * CAP + s];
            stok[tid] = pk >> 2; spk[tid] = pk; sw[tid] = wtk[pk];
        } else {
            stok[tid] = 0; spk[tid] = USE_SCRATCH ? (NTOK * TK) : 0; sw[tid] = 0.f;
        }
    }
    __syncthreads();

    // staging constants (fixed per thread)
    int rowX = tid >> 2;                                  // 0..127
    int cb   = ((tid & 3) * 16) ^ (((rowX >> 1) & 3) << 4);  // pre-swizzled src byte
    const unsigned short* kbase = ktb + (size_t)e * EH * DM;
    const unsigned short* vbase = vtb + (size_t)e * DM * EH;
    const unsigned short* srcX  = xb + (size_t)stok[rowX] * DM + (cb >> 1);
    const unsigned short* srcK0 = kbase + (size_t)rowX * DM + (cb >> 1);
    const unsigned short* srcK1 = kbase + (size_t)(rowX + 128) * DM + (cb >> 1);
    const unsigned short* srcV0 = vbase + (size_t)rowX * EH + (cb >> 1);
    const unsigned short* srcV1 = vbase + (size_t)(rowX + 128) * EH + (cb >> 1);

    auto stage1 = [&](char* Xd, char* Kd, int kc) {
        gload_lds16(srcX + kc,  Xd + w * 1024);
        gload_lds16(srcK0 + kc, Kd + w * 1024);
        gload_lds16(srcK1 + kc, Kd + 8192 + w * 1024);
    };
    auto stageV = [&](char* Kd, int nb, int kc) {
        gload_lds16(srcV0 + nb * 256 * EH + kc, Kd + w * 1024);
        gload_lds16(srcV1 + nb * 256 * EH + kc, Kd + 8192 + w * 1024);
    };

    f32x4 zero = {0.f, 0.f, 0.f, 0.f};
    f32x4 acc[4][4];
    #pragma unroll
    for (int mi = 0; mi < 4; ++mi)
        #pragma unroll
        for (int ni = 0; ni < 4; ++ni) acc[mi][ni] = zero;

    auto comp1 = [&](const char* Xb, const char* Kb) {
        short8 a[4], bb[4];
        #pragma unroll
        for (int mi = 0; mi < 4; ++mi) {
            int row = th * 64 + mi * 16 + lm;
            a[mi] = *(const short8*)(Xb + row * 64 +
                     ((q * 16) ^ (((row >> 1) & 3) << 4)));
        }
        #pragma unroll
        for (int ni = 0; ni < 4; ++ni) {
            int row = hq * 64 + ni * 16 + lm;
            bb[ni] = *(const short8*)(Kb + row * 64 +
                      ((q * 16) ^ (((row >> 1) & 3) << 4)));
        }
        #pragma unroll
        for (int mi = 0; mi < 4; ++mi)
            #pragma unroll
            for (int ni = 0; ni < 4; ++ni)
                acc[mi][ni] = MFMA16(a[mi], bb[ni], acc[mi][ni]);
    };

    // ---- phase 1: S = relu(X @ K_e), pipelined ----
    stage1(Xs0, Ks0, 0);
    __syncthreads();
    for (int s2 = 0; s2 < 16; ++s2) {
        int kc = s2 * 64;                    // elems, 2 steps of 32
        stage1(Xs1, Ks1, kc + 32);
        comp1(Xs0, Ks0);
        __syncthreads();
        if (s2 < 15) stage1(Xs0, Ks0, kc + 64);
        else         stageV(Ks0, 0, 0);      // phase-2 prologue
        comp1(Xs1, Ks1);
        __syncthreads();
    }

    // relu -> Ss (bf16, swizzled); D layout: col=lane&15, row=(lane>>4)*4+r
    #pragma unroll
    for (int mi = 0; mi < 4; ++mi)
        #pragma unroll
        for (int ni = 0; ni < 4; ++ni) {
            f32x4 v = acc[mi][ni];
            #pragma unroll
            for (int r = 0; r < 4; ++r) {
                int row = th * 64 + mi * 16 + q * 4 + r;
                int col = hq * 64 + ni * 16 + lm;
                *(unsigned short*)(Ss + row * 512 +
                    ((col * 2) ^ ((row & 7) << 4))) = f2bf(fmaxf(v[r], 0.f));
            }
        }
    __syncthreads();   // drains V(0) stage + Ss writes

    // preload epilogue metadata into regs (static indexing)
    int spk_[4][4];
    float sw_[4][4];
    int stok_[4][4];
    #pragma unroll
    for (int mi = 0; mi < 4; ++mi)
        #pragma unroll
        for (int r = 0; r < 4; ++r) {
            int slot = th * 64 + mi * 16 + q * 4 + r;
            spk_[mi][r] = spk[slot];
            if (!USE_SCRATCH) { sw_[mi][r] = sw[slot]; stok_[mi][r] = stok[slot]; }
        }

    // ---- phase 2: O = S @ V_e, pipelined; wave: tokens th*64, d = nb*256+hq*64 ----
    int dq = hq;
    for (int nb = 0; nb < 4; ++nb) {
        f32x4 acc2[4][4];
        #pragma unroll
        for (int mi = 0; mi < 4; ++mi)
            #pragma unroll
            for (int ni = 0; ni < 4; ++ni) acc2[mi][ni] = zero;

        auto comp2 = [&](int kc, const char* Vb) {
            short8 a[4], bb[4];
            #pragma unroll
            for (int mi = 0; mi < 4; ++mi) {
                int row = th * 64 + mi * 16 + lm;
                a[mi] = *(const short8*)(Ss + row * 512 +
                         ((kc * 64 + q * 16) ^ ((row & 7) << 4)));
            }
            #pragma unroll
            for (int ni = 0; ni < 4; ++ni) {
                int row = dq * 64 + ni * 16 + lm;
                bb[ni] = *(const short8*)(Vb + row * 64 +
                          ((q * 16) ^ (((row >> 1) & 3) << 4)));
            }
            #pragma unroll
            for (int mi = 0; mi < 4; ++mi)
                #pragma unroll
                for (int ni = 0; ni < 4; ++ni)
                    acc2[mi][ni] = MFMA16(a[mi], bb[ni], acc2[mi][ni]);
        };

        #pragma unroll
        for (int kc8 = 0; kc8 < 8; kc8 += 2) {
            stageV(Ks1, nb, (kc8 + 1) * 32);
            comp2(kc8, Ks0);
            __syncthreads();
            if (kc8 < 6)      stageV(Ks0, nb, (kc8 + 2) * 32);
            else if (nb < 3)  stageV(Ks0, nb + 1, 0);
            comp2(kc8 + 1, Ks1);
            __syncthreads();
        }

        #pragma unroll
        for (int mi = 0; mi < 4; ++mi)
            #pragma unroll
            for (int ni = 0; ni < 4; ++ni) {
                f32x4 v = acc2[mi][ni];
                #pragma unroll
                for (int r = 0; r < 4; ++r) {
                    int d = nb * 256 + dq * 64 + ni * 16 + lm;
                    if (USE_SCRATCH) {
                        scratch[(size_t)spk_[mi][r] * DM + d] = f2bf(v[r]);
                    } else {
                        atomicAdd(out + (size_t)stok_[mi][r] * DM + d,
                                  sw_[mi][r] * v[r]);
                    }
                }
            }
    }
}

// ---------------- combine ----------------
__global__ __launch_bounds__(256) void combine_kernel(
    const unsigned short* __restrict__ scratch, const float* __restrict__ wtk,
    float* __restrict__ out)
{
    int t  = blockIdx.x * 2 + (threadIdx.x >> 7);
    int d0 = (threadIdx.x & 127) * 8;
    float o[8] = {0.f, 0.f, 0.f, 0.f, 0.f, 0.f, 0.f, 0.f};
    #pragma unroll
    for (int k = 0; k < TK; ++k) {
        float wv = wtk[t * TK + k];
        uint4 qv = *(const uint4*)(scratch + (size_t)(t * TK + k) * DM + d0);
        unsigned int us[4] = {qv.x, qv.y, qv.z, qv.w};
        #pragma unroll
        for (int j = 0; j < 4; ++j) {
            o[j * 2 + 0] = fmaf(wv, bf2f((unsigned short)(us[j] & 0xffff)), o[j * 2 + 0]);
            o[j * 2 + 1] = fmaf(wv, bf2f((unsigned short)(us[j] >> 16)),    o[j * 2 + 1]);
        }
    }
    float4 w0 = {o[0], o[1], o[2], o[3]}, w1 = {o[4], o[5], o[6], o[7]};
    *(float4*)(out + (size_t)t * DM + d0)     = w0;
    *(float4*)(out + (size_t)t * DM + d0 + 4) = w1;
}

extern "C" void kernel_launch(void* const* d_in, const int* in_sizes, int n_in,
                              void* d_out, int out_size, void* d_ws, size_t ws_size,
                              hipStream_t stream) {
    const float* x      = (const float*)d_in[0];
    const float* esel   = (const float*)d_in[1];
    const float* keys   = (const float*)d_in[2];
    const float* values = (const float*)d_in[3];
    const float* rscale = (const float*)d_in[4];
    float* out = (float*)d_out;

    char* ws = (char*)d_ws;
    size_t o = 0;
    auto alloc = [&](size_t sz) { size_t r = o; o = (o + sz + 255) & ~(size_t)255; return r; };
    size_t o_counts = alloc(NE * 4);
    size_t o_lpk    = alloc((size_t)NE * CAP * 4);
    size_t o_sel4   = alloc((size_t)NTOK * 16);
    size_t o_wtk    = alloc((size_t)NTOK * TK * 4);
    size_t o_xb     = alloc((size_t)NTOK * DM * 2);
    size_t o_ktb    = alloc((size_t)NE * EH * DM * 2);
    size_t o_vtb    = alloc((size_t)NE * DM * EH * 2);
    size_t o_scr    = alloc(((size_t)NTOK * TK + BM) * DM * 2);
    size_t need_full = o;

    int*            counts  = (int*)(ws + o_counts);
    int*            lpk     = (int*)(ws + o_lpk);
    int4*           sel4    = (int4*)(ws + o_sel4);
    float*          wtk     = (float*)(ws + o_wtk);
    unsigned short* xb      = (unsigned short*)(ws + o_xb);
    unsigned short* ktb     = (unsigned short*)(ws + o_ktb);
    unsigned short* vtb     = (unsigned short*)(ws + o_vtb);
    unsigned short* scratch = (unsigned short*)(ws + o_scr);

    bool use_scratch = ws_size >= need_full;

    if (!use_scratch)
        hipMemsetAsync(d_out, 0, (size_t)out_size * sizeof(float), stream);

    route_conv_kernel<<<NTOK / 8, 256, 0, stream>>>(x, esel, rscale, xb,
                                                    sel4, wtk);
    compact_kernel<<<NE, 1024, 0, stream>>>(sel4, counts, lpk);
    trans_kernel<<<dim3(EH / 32, DM / 32, NE), 256, 0, stream>>>(keys, ktb, DM, EH);
    trans_kernel<<<dim3(DM / 32, EH / 32, NE), 256, 0, stream>>>(values, vtb, EH, DM);

    if (use_scratch) {
        ffn_kernel<1><<<1024, 512, 0, stream>>>(
            xb, ktb, vtb, counts, lpk, wtk, scratch, out);
        combine_kernel<<<NTOK / 2, 256, 0, stream>>>(scratch, wtk, out);
    } else {
        ffn_kernel<0><<<1024, 512, 0, stream>>>(
            xb, ktb, vtb, counts, lpk, wtk, scratch, out);
    }
}

// Round 7
// 140.044 us; speedup vs baseline: 1.4736x; 1.0284x over previous
//
#include <hip/hip_runtime.h>
#include <math.h>

// SigmaMoE bf16-MFMA version, round 7.
// Pipeline (NO global atomics):
//  route_conv: fused x->bf16 convert + fp32 routing + exact top-4
//  compact:    per-expert lists via ballot-scan (deterministic)
//  trans:      keys -> ktb bf16 [16][256][1024]; values -> vtb bf16 [16][1024][256]
//  ffn<1>:     dynamic expert/tile mapping from counts (grid 384 = 8 pairs x 48),
//              3-buffer counted-vmcnt pipeline (T3/T4): one raw s_barrier per
//              32-K step, s_waitcnt vmcnt(3/2) (never 0 until the end).
//  combine:    out[t] = sum_k wtk[t*4+k] * scratch[t*4+k]

constexpr int NTOK = 8192;
constexpr int DM   = 1024;
constexpr int NE   = 16;
constexpr int EH   = 256;
constexpr int TK   = 4;
constexpr int CAP  = 8192;
constexpr int BM   = 128;

typedef __attribute__((ext_vector_type(8))) short short8;
typedef __attribute__((ext_vector_type(4))) float f32x4;

#define MFMA16(a, b, c) __builtin_amdgcn_mfma_f32_16x16x32_bf16(a, b, c, 0, 0, 0)
#define VMCNT(n) asm volatile("s_waitcnt vmcnt(" #n ")" ::: "memory")
#define LGKM0    asm volatile("s_waitcnt lgkmcnt(0)" ::: "memory")
#define SBAR     __builtin_amdgcn_s_barrier()
#define SCHED0   __builtin_amdgcn_sched_barrier(0)

__device__ __forceinline__ void gload_lds16(const void* g, void* l) {
    __builtin_amdgcn_global_load_lds(
        (const __attribute__((address_space(1))) void*)g,
        (__attribute__((address_space(3))) void*)l, 16, 0, 0);
}

__device__ __forceinline__ unsigned short f2bf(float f) {
    union { float f; unsigned int u; } x; x.f = f;
    unsigned int r = x.u + 0x7fffu + ((x.u >> 16) & 1u);  // RNE
    return (unsigned short)(r >> 16);
}
__device__ __forceinline__ float bf2f(unsigned short b) {
    union { unsigned int u; float f; } x; x.u = ((unsigned int)b) << 16;
    return x.f;
}

// ---------------- fused convert + routing (atomic-free) ----------------
__global__ __launch_bounds__(256) void route_conv_kernel(
    const float* __restrict__ x, const float* __restrict__ esel,
    const float* __restrict__ rscale,
    unsigned short* __restrict__ xb,
    int4* __restrict__ sel4, float* __restrict__ wtk)
{
    __shared__ float Es[NE * DM];   // 64KB
    int tid = threadIdx.x;

    {   // stage esel: 4096 float4s
        const float4* src = (const float4*)esel;
        float4* dst = (float4*)Es;
        #pragma unroll
        for (int j = 0; j < 16; ++j) dst[tid + j * 256] = src[tid + j * 256];
    }
    __syncthreads();

    int t    = blockIdx.x * 8 + (tid >> 5);
    int l32  = tid & 31;

    float acc[NE];
    #pragma unroll
    for (int e = 0; e < NE; ++e) acc[e] = 0.f;

    const float4* x4 = (const float4*)(x + (size_t)t * DM);
    const float4* E4 = (const float4*)Es;
    #pragma unroll
    for (int i4 = 0; i4 < 8; ++i4) {
        int d4 = i4 * 32 + l32;
        float4 xv = x4[d4];
        ushort4 cb = { f2bf(xv.x), f2bf(xv.y), f2bf(xv.z), f2bf(xv.w) };
        *(ushort4*)(xb + (size_t)t * DM + d4 * 4) = cb;
        #pragma unroll
        for (int e = 0; e < NE; ++e) {
            float4 wv = E4[e * 256 + d4];
            acc[e] = fmaf(xv.x, wv.x, acc[e]);
            acc[e] = fmaf(xv.y, wv.y, acc[e]);
            acc[e] = fmaf(xv.z, wv.z, acc[e]);
            acc[e] = fmaf(xv.w, wv.w, acc[e]);
        }
    }

    #pragma unroll
    for (int off = 16; off; off >>= 1)
        #pragma unroll
        for (int e = 0; e < NE; ++e)
            acc[e] += __shfl_xor(acc[e], off, 32);

    if (l32 == 0) {
        float p[NE];
        #pragma unroll
        for (int e = 0; e < NE; ++e) p[e] = 1.0f / (1.0f + expf(-acc[e]));

        int   sel_e[TK];
        float sel_p[TK];
        float sum = 0.f;
        #pragma unroll
        for (int k = 0; k < TK; ++k) {
            float best = -INFINITY; int be = NE;
            #pragma unroll
            for (int e = 0; e < NE; ++e) {
                bool take = p[e] > best;
                best = take ? p[e] : best;
                be   = take ? e    : be;
            }
            sel_e[k] = be; sel_p[k] = best; sum += best;
            #pragma unroll
            for (int e = 0; e < NE; ++e) p[e] = (e == be) ? -INFINITY : p[e];
        }

        float wsc = rscale[0] / fmaxf(sum, 1e-9f);
        int4 s = { sel_e[0], sel_e[1], sel_e[2], sel_e[3] };
        sel4[t] = s;
        float4 wv = { sel_p[0] * wsc, sel_p[1] * wsc,
                      sel_p[2] * wsc, sel_p[3] * wsc };
        *(float4*)(wtk + t * TK) = wv;
    }
}

// ---------------- compact: per-expert lists, atomic-free ----------------
__global__ __launch_bounds__(1024) void compact_kernel(
    const int4* __restrict__ sel4, int* __restrict__ counts,
    int* __restrict__ lpk)
{
    __shared__ int wsum[16];
    int e    = blockIdx.x;
    int tid  = threadIdx.x;
    int w    = tid >> 6;
    int lane = tid & 63;

    int base = 0;
    for (int c = 0; c < NTOK; c += 1024) {
        int t = c + tid;
        int4 s = sel4[t];
        int k = -1;
        if      (s.x == e) k = 0;
        else if (s.y == e) k = 1;
        else if (s.z == e) k = 2;
        else if (s.w == e) k = 3;
        unsigned long long m = __ballot(k >= 0);
        int rank = __popcll(m & ((1ull << lane) - 1ull));
        if (lane == 63) wsum[w] = __popcll(m);
        __syncthreads();
        int prefix = 0, total = 0;
        #pragma unroll
        for (int i = 0; i < 16; ++i) {
            int v = wsum[i];
            prefix += (i < w) ? v : 0;
            total  += v;
        }
        if (k >= 0) lpk[e * CAP + base + prefix + rank] = t * TK + k;
        base += total;
        __syncthreads();
    }
    if (tid == 0) counts[e] = base;
}

// in [E][R][C] f32 -> out [E][C][R] bf16
__global__ __launch_bounds__(256) void trans_kernel(
    const float* __restrict__ in, unsigned short* __restrict__ outp, int R, int C)
{
    __shared__ float T[32][33];
    int e = blockIdx.z;
    int r0 = blockIdx.y * 32, c0 = blockIdx.x * 32;
    int ri = threadIdx.x >> 3, cq = threadIdx.x & 7;
    float4 v = *(const float4*)(in + ((size_t)e * R + r0 + ri) * C + c0 + cq * 4);
    T[ri][cq * 4 + 0] = v.x; T[ri][cq * 4 + 1] = v.y;
    T[ri][cq * 4 + 2] = v.z; T[ri][cq * 4 + 3] = v.w;
    __syncthreads();
    int ci = threadIdx.x >> 3, rq = threadIdx.x & 7;
    ushort4 o = { f2bf(T[rq * 4 + 0][ci]), f2bf(T[rq * 4 + 1][ci]),
                  f2bf(T[rq * 4 + 2][ci]), f2bf(T[rq * 4 + 3][ci]) };
    *(ushort4*)(outp + ((size_t)e * C + c0 + ci) * R + r0 + rq * 4) = o;
}

// ---------------- FFN (MFMA, counted-vmcnt 3-buffer pipeline) ----------------
// 512 threads (8 waves). Grid 384 = 8 XCD-pairs x 48 slots; block derives
// (e, t0) from counts. LDS: 3 x 24KB stage buffers (X 8KB + K/V 16KB),
// Ss 64KB, meta 1.5KB = 140.8KB.
// Per 32-K step: VMCNT(3|2) -> s_barrier -> issue stage(n+2) -> MFMA.
template<int USE_SCRATCH>
__global__ __launch_bounds__(512, 2) void ffn_kernel(
    const unsigned short* __restrict__ xb,
    const unsigned short* __restrict__ ktb,   // [16][256][1024]
    const unsigned short* __restrict__ vtb,   // [16][1024][256]
    const int* __restrict__ counts, const int* __restrict__ lpk,
    const float* __restrict__ wtk,
    unsigned short* __restrict__ scratch,     // [NTOK*TK+BM][1024] bf16
    float* __restrict__ out)
{
    constexpr int BUF  = 24576;
    constexpr int META = 3 * BUF + 65536;
    __shared__ __align__(16) char L[3 * BUF + 65536 + 1536];
    char* const Ss = L + 3 * BUF;              // 64KB
    int*   stok = (int*)(L + META);
    int*   spk  = (int*)(L + META + 512);
    float* sw   = (float*)(L + META + 1024);

    int tid  = threadIdx.x;
    int lane = tid & 63;
    int w    = tid >> 6;
    int lm   = lane & 15;
    int q    = lane >> 4;
    int th   = w >> 2;      // token half (0,1)
    int hq   = w & 3;       // h/d quarter (0..3)

    int xp = blockIdx.x & 7;        // expert pair (== XCD under %8 round-robin)
    int j0 = blockIdx.x >> 3;       // 0..47
    int e0 = xp * 2;
    int c0 = counts[e0], c1 = counts[e0 + 1];
    int n0 = (c0 + BM - 1) >> 7;
    int ntot = n0 + ((c1 + BM - 1) >> 7);

    for (int jt = j0; jt < ntot; jt += 48) {
        int e, t0, cnt;
        if (jt < n0) { e = e0;     t0 = jt << 7;        cnt = c0; }
        else         { e = e0 + 1; t0 = (jt - n0) << 7; cnt = c1; }

        // ---- per-tile metadata ----
        if (tid < BM) {
            int s = t0 + tid;
            if (s < cnt) {
                int pk = lpk[e * CAP + s];
                stok[tid] = pk >> 2; spk[tid] = pk; sw[tid] = wtk[pk];
            } else {
                stok[tid] = 0; spk[tid] = USE_SCRATCH ? (NTOK * TK) : 0; sw[tid] = 0.f;
            }
        }
        LGKM0;
        SBAR;              // meta visible; prior iteration's buffer reads done
        SCHED0;

        int rowX = tid >> 2;
        int cb   = ((tid & 3) * 16) ^ (((rowX >> 1) & 3) << 4);
        const unsigned short* kbase = ktb + (size_t)e * EH * DM;
        const unsigned short* vbase = vtb + (size_t)e * DM * EH;
        const unsigned short* srcX  = xb + (size_t)stok[rowX] * DM + (cb >> 1);
        const unsigned short* srcK0 = kbase + (size_t)rowX * DM + (cb >> 1);
        const unsigned short* srcK1 = kbase + (size_t)(rowX + 128) * DM + (cb >> 1);
        const unsigned short* srcV0 = vbase + (size_t)rowX * EH + (cb >> 1);
        const unsigned short* srcV1 = vbase + (size_t)(rowX + 128) * EH + (cb >> 1);

        auto stage1 = [&](char* buf, int kc) {          // 3 loads/thread
            gload_lds16(srcX + kc,  buf + w * 1024);
            gload_lds16(srcK0 + kc, buf + 8192 + w * 1024);
            gload_lds16(srcK1 + kc, buf + 16384 + w * 1024);
        };
        auto stageV = [&](char* buf, int nb, int kc) {  // 2 loads/thread
            gload_lds16(srcV0 + nb * 256 * EH + kc, buf + w * 1024);
            gload_lds16(srcV1 + nb * 256 * EH + kc, buf + 8192 + w * 1024);
        };

        f32x4 zero = {0.f, 0.f, 0.f, 0.f};
        f32x4 acc[4][4];
        #pragma unroll
        for (int mi = 0; mi < 4; ++mi)
            #pragma unroll
            for (int ni = 0; ni < 4; ++ni) acc[mi][ni] = zero;

        auto comp1 = [&](const char* buf) {
            const char* Kb = buf + 8192;
            short8 a[4], bb[4];
            #pragma unroll
            for (int mi = 0; mi < 4; ++mi) {
                int row = th * 64 + mi * 16 + lm;
                a[mi] = *(const short8*)(buf + row * 64 +
                         ((q * 16) ^ (((row >> 1) & 3) << 4)));
            }
            #pragma unroll
            for (int ni = 0; ni < 4; ++ni) {
                int row = hq * 64 + ni * 16 + lm;
                bb[ni] = *(const short8*)(Kb + row * 64 +
                          ((q * 16) ^ (((row >> 1) & 3) << 4)));
            }
            #pragma unroll
            for (int mi = 0; mi < 4; ++mi)
                #pragma unroll
                for (int ni = 0; ni < 4; ++ni)
                    acc[mi][ni] = MFMA16(a[mi], bb[ni], acc[mi][ni]);
        };

        // ---- phase 1: S = relu(X @ K_e), 32 steps of K=32 ----
        stage1(L, 0);
        stage1(L + BUF, 32);
        for (int n = 0; n < 30; ++n) {
            VMCNT(3); SBAR; SCHED0;
            stage1(L + ((n + 2) % 3) * BUF, (n + 2) * 32);
            __builtin_amdgcn_s_setprio(1);
            comp1(L + (n % 3) * BUF);
            __builtin_amdgcn_s_setprio(0);
        }
        // n=30: prefetch V stage 32 (buf2); n=31: V stage 33 (buf0)
        VMCNT(3); SBAR; SCHED0;
        stageV(L + 2 * BUF, 0, 0);
        __builtin_amdgcn_s_setprio(1);
        comp1(L);
        __builtin_amdgcn_s_setprio(0);
        VMCNT(2); SBAR; SCHED0;
        stageV(L, 0, 32);
        __builtin_amdgcn_s_setprio(1);
        comp1(L + BUF);
        __builtin_amdgcn_s_setprio(0);

        // relu -> Ss (bf16, swizzled); D layout: col=lane&15, row=(lane>>4)*4+r
        #pragma unroll
        for (int mi = 0; mi < 4; ++mi)
            #pragma unroll
            for (int ni = 0; ni < 4; ++ni) {
                f32x4 v = acc[mi][ni];
                #pragma unroll
                for (int r = 0; r < 4; ++r) {
                    int row = th * 64 + mi * 16 + q * 4 + r;
                    int col = hq * 64 + ni * 16 + lm;
                    *(unsigned short*)(Ss + row * 512 +
                        ((col * 2) ^ ((row & 7) << 4))) = f2bf(fmaxf(v[r], 0.f));
                }
            }
        LGKM0;   // own Ss writes complete; cross-wave via next barrier

        // epilogue metadata in registers (static indexing)
        int   spk_[4][4];
        float sw_[4][4];
        int   stok_[4][4];
        #pragma unroll
        for (int mi = 0; mi < 4; ++mi)
            #pragma unroll
            for (int r = 0; r < 4; ++r) {
                int slot = th * 64 + mi * 16 + q * 4 + r;
                spk_[mi][r] = spk[slot];
                if (!USE_SCRATCH) { sw_[mi][r] = sw[slot]; stok_[mi][r] = stok[slot]; }
            }

        // ---- phase 2: O = S @ V_e, 32 steps (4 nb groups x 8) ----
        for (int nb = 0; nb < 4; ++nb) {
            f32x4 acc2[4][4];
            #pragma unroll
            for (int mi = 0; mi < 4; ++mi)
                #pragma unroll
                for (int ni = 0; ni < 4; ++ni) acc2[mi][ni] = zero;

            #pragma unroll
            for (int j2 = 0; j2 < 8; ++j2) {
                int u = nb * 8 + j2;
                if (u == 31) { VMCNT(0); } else { VMCNT(2); }
                SBAR; SCHED0;
                if (u < 30) {
                    int u2 = u + 2;
                    stageV(L + ((u + 1) % 3) * BUF, u2 >> 3, (u2 & 7) * 32);
                }
                const char* Vb = L + ((u + 2) % 3) * BUF;
                short8 a[4], bb[4];
                #pragma unroll
                for (int mi = 0; mi < 4; ++mi) {
                    int row = th * 64 + mi * 16 + lm;
                    a[mi] = *(const short8*)(Ss + row * 512 +
                             ((j2 * 64 + q * 16) ^ ((row & 7) << 4)));
                }
                #pragma unroll
                for (int ni = 0; ni < 4; ++ni) {
                    int row = hq * 64 + ni * 16 + lm;
                    bb[ni] = *(const short8*)(Vb + row * 64 +
                              ((q * 16) ^ (((row >> 1) & 3) << 4)));
                }
                __builtin_amdgcn_s_setprio(1);
                #pragma unroll
                for (int mi = 0; mi < 4; ++mi)
                    #pragma unroll
                    for (int ni = 0; ni < 4; ++ni)
                        acc2[mi][ni] = MFMA16(a[mi], bb[ni], acc2[mi][ni]);
                __builtin_amdgcn_s_setprio(0);
            }

            #pragma unroll
            for (int mi = 0; mi < 4; ++mi)
                #pragma unroll
                for (int ni = 0; ni < 4; ++ni) {
                    f32x4 v = acc2[mi][ni];
                    #pragma unroll
                    for (int r = 0; r < 4; ++r) {
                        int d = nb * 256 + hq * 64 + ni * 16 + lm;
                        if (USE_SCRATCH) {
                            scratch[(size_t)spk_[mi][r] * DM + d] = f2bf(v[r]);
                        } else {
                            atomicAdd(out + (size_t)stok_[mi][r] * DM + d,
                                      sw_[mi][r] * v[r]);
                        }
                    }
                }
        }
    }
}

// ---------------- combine ----------------
__global__ __launch_bounds__(256) void combine_kernel(
    const unsigned short* __restrict__ scratch, const float* __restrict__ wtk,
    float* __restrict__ out)
{
    int t  = blockIdx.x * 2 + (threadIdx.x >> 7);
    int d0 = (threadIdx.x & 127) * 8;
    float o[8] = {0.f, 0.f, 0.f, 0.f, 0.f, 0.f, 0.f, 0.f};
    #pragma unroll
    for (int k = 0; k < TK; ++k) {
        float wv = wtk[t * TK + k];
        uint4 qv = *(const uint4*)(scratch + (size_t)(t * TK + k) * DM + d0);
        unsigned int us[4] = {qv.x, qv.y, qv.z, qv.w};
        #pragma unroll
        for (int j = 0; j < 4; ++j) {
            o[j * 2 + 0] = fmaf(wv, bf2f((unsigned short)(us[j] & 0xffff)), o[j * 2 + 0]);
            o[j * 2 + 1] = fmaf(wv, bf2f((unsigned short)(us[j] >> 16)),    o[j * 2 + 1]);
        }
    }
    float4 w0 = {o[0], o[1], o[2], o[3]}, w1 = {o[4], o[5], o[6], o[7]};
    *(float4*)(out + (size_t)t * DM + d0)     = w0;
    *(float4*)(out + (size_t)t * DM + d0 + 4) = w1;
}

extern "C" void kernel_launch(void* const* d_in, const int* in_sizes, int n_in,
                              void* d_out, int out_size, void* d_ws, size_t ws_size,
                              hipStream_t stream) {
    const float* x      = (const float*)d_in[0];
    const float* esel   = (const float*)d_in[1];
    const float* keys   = (const float*)d_in[2];
    const float* values = (const float*)d_in[3];
    const float* rscale = (const float*)d_in[4];
    float* out = (float*)d_out;

    char* ws = (char*)d_ws;
    size_t o = 0;
    auto alloc = [&](size_t sz) { size_t r = o; o = (o + sz + 255) & ~(size_t)255; return r; };
    size_t o_counts = alloc(NE * 4);
    size_t o_lpk    = alloc((size_t)NE * CAP * 4);
    size_t o_sel4   = alloc((size_t)NTOK * 16);
    size_t o_wtk    = alloc((size_t)NTOK * TK * 4);
    size_t o_xb     = alloc((size_t)NTOK * DM * 2);
    size_t o_ktb    = alloc((size_t)NE * EH * DM * 2);
    size_t o_vtb    = alloc((size_t)NE * DM * EH * 2);
    size_t o_scr    = alloc(((size_t)NTOK * TK + BM) * DM * 2);
    size_t need_full = o;

    int*            counts  = (int*)(ws + o_counts);
    int*            lpk     = (int*)(ws + o_lpk);
    int4*           sel4    = (int4*)(ws + o_sel4);
    float*          wtk     = (float*)(ws + o_wtk);
    unsigned short* xb      = (unsigned short*)(ws + o_xb);
    unsigned short* ktb     = (unsigned short*)(ws + o_ktb);
    unsigned short* vtb     = (unsigned short*)(ws + o_vtb);
    unsigned short* scratch = (unsigned short*)(ws + o_scr);

    bool use_scratch = ws_size >= need_full;

    if (!use_scratch)
        hipMemsetAsync(d_out, 0, (size_t)out_size * sizeof(float), stream);

    route_conv_kernel<<<NTOK / 8, 256, 0, stream>>>(x, esel, rscale, xb,
                                                    sel4, wtk);
    compact_kernel<<<NE, 1024, 0, stream>>>(sel4, counts, lpk);
    trans_kernel<<<dim3(EH / 32, DM / 32, NE), 256, 0, stream>>>(keys, ktb, DM, EH);
    trans_kernel<<<dim3(DM / 32, EH / 32, NE), 256, 0, stream>>>(values, vtb, EH, DM);

    if (use_scratch) {
        ffn_kernel<1><<<384, 512, 0, stream>>>(
            xb, ktb, vtb, counts, lpk, wtk, scratch, out);
        combine_kernel<<<NTOK / 2, 256, 0, stream>>>(scratch, wtk, out);
    } else {
        ffn_kernel<0><<<384, 512, 0, stream>>>(
            xb, ktb, vtb, counts, lpk, wtk, scratch, out);
    }
}

// Round 9
// 138.188 us; speedup vs baseline: 1.4934x; 1.0134x over previous
//
#include <hip/hip_runtime.h>
#include <math.h>

// SigmaMoE bf16-MFMA version, round 9 (= R8 structure, transF lane-map FIXED).
//  - Weights in FRAGMENT-BLOCKED layouts ktbF/vtbF [e][tile16][k32][lane][8]:
//    lane = ((k>>3)&3)*16 + (row&15)  <-- the R8 bug was this map transposed.
//  - B-operands load straight into registers (2-deep prefetch, coalesced 1KB).
//  - Phase 2 barrier-free; epilogue packed uint2 stores in permuted scratch.

constexpr int NTOK = 8192;
constexpr int DM   = 1024;
constexpr int NE   = 16;
constexpr int EH   = 256;
constexpr int TK   = 4;
constexpr int CAP  = 8192;
constexpr int BM   = 64;

typedef __attribute__((ext_vector_type(8))) short short8;
typedef __attribute__((ext_vector_type(4))) float f32x4;

#define MFMA16(a, b, c) __builtin_amdgcn_mfma_f32_16x16x32_bf16(a, b, c, 0, 0, 0)
#define VMCNT(n) asm volatile("s_waitcnt vmcnt(" #n ")" ::: "memory")
#define SBAR     __builtin_amdgcn_s_barrier()
#define SCHED0   __builtin_amdgcn_sched_barrier(0)

__device__ __forceinline__ void gload_lds16(const void* g, void* l) {
    __builtin_amdgcn_global_load_lds(
        (const __attribute__((address_space(1))) void*)g,
        (__attribute__((address_space(3))) void*)l, 16, 0, 0);
}

__device__ __forceinline__ unsigned short f2bf(float f) {
    union { float f; unsigned int u; } x; x.f = f;
    unsigned int r = x.u + 0x7fffu + ((x.u >> 16) & 1u);  // RNE
    return (unsigned short)(r >> 16);
}
__device__ __forceinline__ float bf2f(unsigned short b) {
    union { unsigned int u; float f; } x; x.u = ((unsigned int)b) << 16;
    return x.f;
}

// ---------------- fused convert + routing (atomic-free) ----------------
__global__ __launch_bounds__(256) void route_conv_kernel(
    const float* __restrict__ x, const float* __restrict__ esel,
    const float* __restrict__ rscale,
    unsigned short* __restrict__ xb,
    int4* __restrict__ sel4, float* __restrict__ wtk)
{
    __shared__ float Es[NE * DM];   // 64KB
    int tid = threadIdx.x;

    {   // stage esel: 4096 float4s
        const float4* src = (const float4*)esel;
        float4* dst = (float4*)Es;
        #pragma unroll
        for (int j = 0; j < 16; ++j) dst[tid + j * 256] = src[tid + j * 256];
    }
    __syncthreads();

    int t    = blockIdx.x * 8 + (tid >> 5);
    int l32  = tid & 31;

    float acc[NE];
    #pragma unroll
    for (int e = 0; e < NE; ++e) acc[e] = 0.f;

    const float4* x4 = (const float4*)(x + (size_t)t * DM);
    const float4* E4 = (const float4*)Es;
    #pragma unroll
    for (int i4 = 0; i4 < 8; ++i4) {
        int d4 = i4 * 32 + l32;
        float4 xv = x4[d4];
        ushort4 cb = { f2bf(xv.x), f2bf(xv.y), f2bf(xv.z), f2bf(xv.w) };
        *(ushort4*)(xb + (size_t)t * DM + d4 * 4) = cb;
        #pragma unroll
        for (int e = 0; e < NE; ++e) {
            float4 wv = E4[e * 256 + d4];
            acc[e] = fmaf(xv.x, wv.x, acc[e]);
            acc[e] = fmaf(xv.y, wv.y, acc[e]);
            acc[e] = fmaf(xv.z, wv.z, acc[e]);
            acc[e] = fmaf(xv.w, wv.w, acc[e]);
        }
    }

    #pragma unroll
    for (int off = 16; off; off >>= 1)
        #pragma unroll
        for (int e = 0; e < NE; ++e)
            acc[e] += __shfl_xor(acc[e], off, 32);

    if (l32 == 0) {
        float p[NE];
        #pragma unroll
        for (int e = 0; e < NE; ++e) p[e] = 1.0f / (1.0f + expf(-acc[e]));

        int   sel_e[TK];
        float sel_p[TK];
        float sum = 0.f;
        #pragma unroll
        for (int k = 0; k < TK; ++k) {
            float best = -INFINITY; int be = NE;
            #pragma unroll
            for (int e = 0; e < NE; ++e) {
                bool take = p[e] > best;
                best = take ? p[e] : best;
                be   = take ? e    : be;
            }
            sel_e[k] = be; sel_p[k] = best; sum += best;
            #pragma unroll
            for (int e = 0; e < NE; ++e) p[e] = (e == be) ? -INFINITY : p[e];
        }

        float wsc = rscale[0] / fmaxf(sum, 1e-9f);
        int4 s = { sel_e[0], sel_e[1], sel_e[2], sel_e[3] };
        sel4[t] = s;
        float4 wv = { sel_p[0] * wsc, sel_p[1] * wsc,
                      sel_p[2] * wsc, sel_p[3] * wsc };
        *(float4*)(wtk + t * TK) = wv;
    }
}

// ---------------- compact: per-expert lists, atomic-free ----------------
__global__ __launch_bounds__(1024) void compact_kernel(
    const int4* __restrict__ sel4, int* __restrict__ counts,
    int* __restrict__ lpk)
{
    __shared__ int wsum[16];
    int e    = blockIdx.x;
    int tid  = threadIdx.x;
    int w    = tid >> 6;
    int lane = tid & 63;

    int base = 0;
    for (int c = 0; c < NTOK; c += 1024) {
        int t = c + tid;
        int4 s = sel4[t];
        int k = -1;
        if      (s.x == e) k = 0;
        else if (s.y == e) k = 1;
        else if (s.z == e) k = 2;
        else if (s.w == e) k = 3;
        unsigned long long m = __ballot(k >= 0);
        int rank = __popcll(m & ((1ull << lane) - 1ull));
        if (lane == 63) wsum[w] = __popcll(m);
        __syncthreads();
        int prefix = 0, total = 0;
        #pragma unroll
        for (int i = 0; i < 16; ++i) {
            int v = wsum[i];
            prefix += (i < w) ? v : 0;
            total  += v;
        }
        if (k >= 0) lpk[e * CAP + base + prefix + rank] = t * TK + k;
        base += total;
        __syncthreads();
    }
    if (tid == 0) counts[e] = base;
}

// -------- transpose to fragment-blocked layout --------
// in [E][R][C] f32  ->  out [E][C/16][R/32][64 lanes][8] bf16
// element (row_out = c, k = r) stored at chunk (c>>4, r>>5),
// lane = ((r>>3)&3)*16 + (c&15)   [FIXED: was transposed], byte j = r&7.
__global__ __launch_bounds__(256) void transF_kernel(
    const float* __restrict__ in, unsigned short* __restrict__ outp, int R, int C)
{
    __shared__ float T[32][33];
    int e = blockIdx.z;
    int r0 = blockIdx.y * 32, c0 = blockIdx.x * 32;
    int ri = threadIdx.x >> 3, cq = threadIdx.x & 7;
    float4 v = *(const float4*)(in + ((size_t)e * R + r0 + ri) * C + c0 + cq * 4);
    T[ri][cq * 4 + 0] = v.x; T[ri][cq * 4 + 1] = v.y;
    T[ri][cq * 4 + 2] = v.z; T[ri][cq * 4 + 3] = v.w;
    __syncthreads();
    int ci = threadIdx.x >> 3, rq = threadIdx.x & 7;
    int row = c0 + ci;                 // output row (C-dim)
    int kb  = r0 + rq * 4;             // k base (R-dim), 4-aligned
    int nk32 = R >> 5;
    size_t chunk = (size_t)e * (C >> 4) * nk32 + (size_t)(row >> 4) * nk32 + (kb >> 5);
    size_t off = chunk * 512 +
                 (size_t)(((((kb >> 3) & 3) * 16 + (row & 15)) * 8) + (kb & 7));
    ushort4 o = { f2bf(T[rq * 4 + 0][ci]), f2bf(T[rq * 4 + 1][ci]),
                  f2bf(T[rq * 4 + 2][ci]), f2bf(T[rq * 4 + 3][ci]) };
    *(ushort4*)(outp + off) = o;
}

// ---------------- FFN ----------------
// 256 threads (4 waves); per block: expert e, 64 tokens (grid-stride over tiles).
// Phase 1: X in LDS (3-buf, VMCNT+s_barrier per K=32 step); K from ktbF regs.
// Phase 2: barrier-free; V from vtbF regs (2-deep); S from LDS.
// Epilogue: permuted scratch layout, packed uint2 stores.
template<int USE_SCRATCH>
__global__ __launch_bounds__(256) void ffn_kernel(
    const unsigned short* __restrict__ xb,
    const unsigned short* __restrict__ ktbF,  // [16][16][32][512]
    const unsigned short* __restrict__ vtbF,  // [16][64][8][512]
    const int* __restrict__ counts, const int* __restrict__ lpk,
    const float* __restrict__ wtk,
    unsigned short* __restrict__ scratch,     // [NTOK*TK+64][1024] bf16 (permuted cols)
    float* __restrict__ out)
{
    __shared__ __align__(16) char L[12288 + 32768 + 768];
    char* const Xb = L;                 // 3 x 4KB
    char* const Ss = L + 12288;         // 32KB [64][256] bf16 swizzled
    int*   stok = (int*)(L + 45056);
    int*   spk  = (int*)(L + 45056 + 256);
    float* sw   = (float*)(L + 45056 + 512);

    int tid  = threadIdx.x;
    int lane = tid & 63;
    int w    = tid >> 6;                // wave 0..3
    int lm   = lane & 15;
    int q    = lane >> 4;
    int lane8 = lane * 8;

    int xp = blockIdx.x & 7;            // expert pair
    int j0 = blockIdx.x >> 3;           // 0..63
    int e0 = xp * 2;
    int c0 = counts[e0], c1 = counts[e0 + 1];
    int n0 = (c0 + BM - 1) >> 6;
    int ntot = n0 + ((c1 + BM - 1) >> 6);

    for (int jt = j0; jt < ntot; jt += 64) {
        int e, t0, cnt;
        if (jt < n0) { e = e0;     t0 = jt << 6;        cnt = c0; }
        else         { e = e0 + 1; t0 = (jt - n0) << 6; cnt = c1; }

        if (tid < BM) {
            int s = t0 + tid;
            if (s < cnt) {
                int pk = lpk[e * CAP + s];
                stok[tid] = pk >> 2; spk[tid] = pk; sw[tid] = wtk[pk];
            } else {
                stok[tid] = 0; spk[tid] = USE_SCRATCH ? (NTOK * TK) : 0; sw[tid] = 0.f;
            }
        }
        __syncthreads();

        // staging constants
        int rowX = tid >> 2;                                      // 0..63
        int cb   = ((tid & 3) * 16) ^ (((rowX >> 1) & 3) << 4);   // pre-swizzled src byte
        const unsigned short* srcX = xb + (size_t)stok[rowX] * DM + (cb >> 1);
        const unsigned short* kfe  = ktbF + (size_t)e * 262144;
        const unsigned short* vfe  = vtbF + (size_t)e * 262144;
        int w4  = w * 4;
        int w16 = w * 16;

        auto stageX = [&](int n) {
            if (n < 32)
                gload_lds16(srcX + n * 32, Xb + (n % 3) * 4096 + tid * 16);
        };
        auto loadK = [&](short8 (&kr)[4], int n) {
            if (n < 32) {
                #pragma unroll
                for (int ni = 0; ni < 4; ++ni)
                    kr[ni] = *(const short8*)(kfe + (((w4 + ni) * 32 + n) << 9) + lane8);
            }
        };

        f32x4 zero = {0.f, 0.f, 0.f, 0.f};
        f32x4 acc[4][4];
        #pragma unroll
        for (int mi = 0; mi < 4; ++mi)
            #pragma unroll
            for (int ni = 0; ni < 4; ++ni) acc[mi][ni] = zero;

        short8 krA[4], krB[4];

        // prologue: X0, X1, K0 | K1
        stageX(0); stageX(1); loadK(krA, 0);
        SCHED0;
        loadK(krB, 1);
        SCHED0;

        auto step1 = [&](int n, short8 (&kr)[4]) {
            if (n == 0)       { VMCNT(4); }
            else if (n == 31) { VMCNT(0); }
            else              { VMCNT(5); }
            SBAR; SCHED0;
            stageX(n + 2);
            const char* XB = Xb + (n % 3) * 4096;
            short8 a[4];
            #pragma unroll
            for (int mi = 0; mi < 4; ++mi) {
                int row = mi * 16 + lm;
                a[mi] = *(const short8*)(XB + row * 64 +
                         ((q * 16) ^ (((row >> 1) & 3) << 4)));
            }
            __builtin_amdgcn_s_setprio(1);
            #pragma unroll
            for (int mi = 0; mi < 4; ++mi)
                #pragma unroll
                for (int ni = 0; ni < 4; ++ni)
                    acc[mi][ni] = MFMA16(a[mi], kr[ni], acc[mi][ni]);
            __builtin_amdgcn_s_setprio(0);
            loadK(kr, n + 2);
        };

        #pragma unroll
        for (int n = 0; n < 32; ++n) {
            if (n & 1) step1(n, krB);
            else       step1(n, krA);
        }

        // epilogue metadata into regs (before the Ss barrier -> race-free)
        int   spk_[4][4];
        float sw_[4][4];
        int   stok_[4][4];
        #pragma unroll
        for (int mi = 0; mi < 4; ++mi)
            #pragma unroll
            for (int r = 0; r < 4; ++r) {
                int slot = mi * 16 + q * 4 + r;
                spk_[mi][r] = spk[slot];
                if (!USE_SCRATCH) { sw_[mi][r] = sw[slot]; stok_[mi][r] = stok[slot]; }
            }

        // relu -> Ss (bf16, swizzled); D frag: col=lane&15, row=(lane>>4)*4+r
        #pragma unroll
        for (int mi = 0; mi < 4; ++mi)
            #pragma unroll
            for (int ni = 0; ni < 4; ++ni) {
                f32x4 v = acc[mi][ni];
                #pragma unroll
                for (int r = 0; r < 4; ++r) {
                    int row = mi * 16 + q * 4 + r;
                    int col = w * 64 + ni * 16 + lm;
                    *(unsigned short*)(Ss + row * 512 +
                        ((col * 2) ^ ((row & 7) << 4))) = f2bf(fmaxf(v[r], 0.f));
                }
            }
        __syncthreads();

        // ---- phase 2: barrier-free; wave w owns d in [w*256, +256) ----
        short8 vA[4], vB[4];
        auto loadV = [&](short8 (&vr)[4], int u) {
            if (u < 32) {
                int d16b = w16 + ((u >> 3) << 2);
                int kk = u & 7;
                #pragma unroll
                for (int ni = 0; ni < 4; ++ni)
                    vr[ni] = *(const short8*)(vfe + ((((size_t)(d16b + ni)) * 8 + kk) << 9) + lane8);
            }
        };
        loadV(vA, 0); loadV(vB, 1);

        f32x4 acc2[4][4];
        auto step2 = [&](int u, short8 (&vr)[4]) {
            int kk = u & 7, nb = u >> 3;
            if (kk == 0) {
                #pragma unroll
                for (int mi = 0; mi < 4; ++mi)
                    #pragma unroll
                    for (int ni = 0; ni < 4; ++ni) acc2[mi][ni] = zero;
            }
            short8 a2[4];
            #pragma unroll
            for (int mi = 0; mi < 4; ++mi) {
                int row = mi * 16 + lm;
                a2[mi] = *(const short8*)(Ss + row * 512 +
                          ((kk * 64 + q * 16) ^ ((row & 7) << 4)));
            }
            __builtin_amdgcn_s_setprio(1);
            #pragma unroll
            for (int mi = 0; mi < 4; ++mi)
                #pragma unroll
                for (int ni = 0; ni < 4; ++ni)
                    acc2[mi][ni] = MFMA16(a2[mi], vr[ni], acc2[mi][ni]);
            __builtin_amdgcn_s_setprio(0);
            loadV(vr, u + 2);
            if (kk == 7) {
                // epilogue nb: packed uint2 stores, permuted layout
                #pragma unroll
                for (int mi = 0; mi < 4; ++mi)
                    #pragma unroll
                    for (int r = 0; r < 4; ++r) {
                        if (USE_SCRATCH) {
                            unsigned int lo = (unsigned int)f2bf(acc2[mi][0][r]) |
                                              ((unsigned int)f2bf(acc2[mi][1][r]) << 16);
                            unsigned int hi = (unsigned int)f2bf(acc2[mi][2][r]) |
                                              ((unsigned int)f2bf(acc2[mi][3][r]) << 16);
                            uint2 pv = { lo, hi };
                            *(uint2*)(scratch + (size_t)spk_[mi][r] * DM +
                                      (w4 + nb) * 64 + lm * 4) = pv;
                        } else {
                            #pragma unroll
                            for (int ni = 0; ni < 4; ++ni) {
                                int d = w * 256 + nb * 64 + ni * 16 + lm;
                                atomicAdd(out + (size_t)stok_[mi][r] * DM + d,
                                          sw_[mi][r] * acc2[mi][ni][r]);
                            }
                        }
                    }
            }
        };

        #pragma unroll
        for (int u = 0; u < 32; ++u) {
            if (u & 1) step2(u, vB);
            else       step2(u, vA);
        }
    }
}

// ---------------- combine (inverts the permuted scratch layout) ----------------
// scratch pos within each 64-col block: p = lm*4 + ni  <->  d = ni*16 + lm.
__global__ __launch_bounds__(256) void combine_kernel(
    const unsigned short* __restrict__ scratch, const float* __restrict__ wtk,
    float* __restrict__ out)
{
    int t   = blockIdx.x * 2 + (threadIdx.x >> 7);
    int l   = threadIdx.x & 127;
    int blk = l >> 3;          // 0..15  (64-col block)
    int lm2 = l & 7;           // covers lm = 2*lm2, 2*lm2+1
    float o[8] = {0.f, 0.f, 0.f, 0.f, 0.f, 0.f, 0.f, 0.f};
    #pragma unroll
    for (int k = 0; k < TK; ++k) {
        float wv = wtk[t * TK + k];
        uint4 qv = *(const uint4*)(scratch + (size_t)(t * TK + k) * DM +
                                   blk * 64 + lm2 * 8);
        unsigned int us[4] = { qv.x, qv.y, qv.z, qv.w };
        #pragma unroll
        for (int j = 0; j < 4; ++j) {
            o[j * 2 + 0] = fmaf(wv, bf2f((unsigned short)(us[j] & 0xffff)), o[j * 2 + 0]);
            o[j * 2 + 1] = fmaf(wv, bf2f((unsigned short)(us[j] >> 16)),    o[j * 2 + 1]);
        }
    }
    // idx 0..3: (lm=2*lm2, ni=idx); idx 4..7: (lm=2*lm2+1, ni=idx-4)
    float* ob = out + (size_t)t * DM + blk * 64 + 2 * lm2;
    #pragma unroll
    for (int ni = 0; ni < 4; ++ni) {
        float2 f2 = { o[ni], o[ni + 4] };
        *(float2*)(ob + ni * 16) = f2;
    }
}

extern "C" void kernel_launch(void* const* d_in, const int* in_sizes, int n_in,
                              void* d_out, int out_size, void* d_ws, size_t ws_size,
                              hipStream_t stream) {
    const float* x      = (const float*)d_in[0];
    const float* esel   = (const float*)d_in[1];
    const float* keys   = (const float*)d_in[2];
    const float* values = (const float*)d_in[3];
    const float* rscale = (const float*)d_in[4];
    float* out = (float*)d_out;

    char* ws = (char*)d_ws;
    size_t o = 0;
    auto alloc = [&](size_t sz) { size_t r = o; o = (o + sz + 255) & ~(size_t)255; return r; };
    size_t o_counts = alloc(NE * 4);
    size_t o_lpk    = alloc((size_t)NE * CAP * 4);
    size_t o_sel4   = alloc((size_t)NTOK * 16);
    size_t o_wtk    = alloc((size_t)NTOK * TK * 4);
    size_t o_xb     = alloc((size_t)NTOK * DM * 2);
    size_t o_ktb    = alloc((size_t)NE * EH * DM * 2);
    size_t o_vtb    = alloc((size_t)NE * DM * EH * 2);
    size_t o_scr    = alloc(((size_t)NTOK * TK + BM) * DM * 2);
    size_t need_full = o;

    int*            counts  = (int*)(ws + o_counts);
    int*            lpk     = (int*)(ws + o_lpk);
    int4*           sel4    = (int4*)(ws + o_sel4);
    float*          wtk     = (float*)(ws + o_wtk);
    unsigned short* xb      = (unsigned short*)(ws + o_xb);
    unsigned short* ktbF    = (unsigned short*)(ws + o_ktb);
    unsigned short* vtbF    = (unsigned short*)(ws + o_vtb);
    unsigned short* scratch = (unsigned short*)(ws + o_scr);

    bool use_scratch = ws_size >= need_full;

    if (!use_scratch)
        hipMemsetAsync(d_out, 0, (size_t)out_size * sizeof(float), stream);

    route_conv_kernel<<<NTOK / 8, 256, 0, stream>>>(x, esel, rscale, xb,
                                                    sel4, wtk);
    compact_kernel<<<NE, 1024, 0, stream>>>(sel4, counts, lpk);
    // keys [e][1024(k)][256(h)] -> ktbF chunks (h16, k32): R=1024, C=256
    transF_kernel<<<dim3(EH / 32, DM / 32, NE), 256, 0, stream>>>(keys, ktbF, DM, EH);
    // values [e][256(k)][1024(d)] -> vtbF chunks (d16, k32): R=256, C=1024
    transF_kernel<<<dim3(DM / 32, EH / 32, NE), 256, 0, stream>>>(values, vtbF, EH, DM);

    if (use_scratch) {
        ffn_kernel<1><<<512, 256, 0, stream>>>(
            xb, ktbF, vtbF, counts, lpk, wtk, scratch, out);
        combine_kernel<<<NTOK / 2, 256, 0, stream>>>(scratch, wtk, out);
    } else {
        ffn_kernel<0><<<512, 256, 0, stream>>>(
            xb, ktbF, vtbF, counts, lpk, wtk, scratch, out);
    }
}